// Round 4
// baseline (319.269 us; speedup 1.0000x reference)
//
#include <hip/hip_runtime.h>

// Problem constants
#define G_      52
#define GG_     2704          // G*G
#define CH_     88            // 5+1+C
#define NTOP_   53
#define CTOT_   82
#define PTOT_   259584        // B*A*G*G
#define NTGT_   512
#define WT_     32            // positions per wave-tile
#define NBM_    8112          // PTOT/WT main blocks
#define NBT_    (NBM_ + NTGT_) // total blocks (tgt fused)
#define XCHUNK_ 1014          // NBM_/8 (exact)

typedef float f32x4 __attribute__((ext_vector_type(4)));

__device__ __forceinline__ float sigf(float v) {
    return 1.0f / (1.0f + __expf(-v));
}

// ws layout (doubles):
//  [0..63]   noobj_all partials
//  [64..71]  s512  [72..79] itm  [80..87] ibm
//  [88..95]  nsub  [96..103] hitc  [104..111] itmc  [112..119] ibmc
//  [120]     done-counter (as unsigned int)

// --- main path: one wave transposes an [88][32] tile, no cross-wave sync ---
__device__ __forceinline__ void main_wave(int bid, const float* __restrict__ x,
                                          const float* __restrict__ anchors,
                                          float* __restrict__ out,
                                          double* __restrict__ ws,
                                          float* __restrict__ lds, int lane) {
    const int pbase  = bid * WT_;
    const int posoff = (lane & 7) << 2;       // f4 start within tile
    const int pr     = pbase + posoff;
    const int ba     = pr / GG_;               // f4 never crosses ba (GG%4==0)
    const int q      = pr - ba * GG_;
    const int c0     = lane >> 3;              // 0..7
    const float* src = x + (ba * CH_ + c0) * GG_ + q;

    float noobj = 0.0f;
    #pragma unroll
    for (int i = 0; i < 11; ++i) {
        const int c = c0 + 8 * i;              // covers 0..87 exactly
        f32x4 v = *(const f32x4*)(src + i * 8 * GG_);
        f32x4 tv;
        if (i == 0 && c0 < 4) {                // only iter 0 diverges
            if (c0 == 0) {
                int gx = q % G_;               // q,G_ mult of 4 -> gx+3<=51
                #pragma unroll
                for (int k = 0; k < 4; ++k)
                    tv[k] = ((float)(gx + k) + sigf(v[k])) * 8.0f;
            } else if (c0 == 1) {
                int gy = q / G_;               // constant across the f4
                #pragma unroll
                for (int k = 0; k < 4; ++k)
                    tv[k] = ((float)gy + sigf(v[k])) * 8.0f;
            } else {                           // c0==2 (w) or c0==3 (h)
                int m = ba - (ba / 3) * 3;
                float aw = (m == 0) ? anchors[0] : (m == 1) ? anchors[2] : anchors[4];
                float ah = (m == 0) ? anchors[1] : (m == 1) ? anchors[3] : anchors[5];
                float anc = (c0 == 2) ? aw : ah;
                #pragma unroll
                for (int k = 0; k < 4; ++k)
                    tv[k] = anc * __expf(v[k]) * 416.0f;
            }
        } else {
            #pragma unroll
            for (int k = 0; k < 4; ++k) tv[k] = sigf(v[k]);
            if (i == 0 && c0 == 4) {           // conf channel: no-obj BCE
                #pragma unroll
                for (int k = 0; k < 4; ++k)
                    noobj -= fmaxf(log1pf(-tv[k]), -100.0f);
            }
        }
        // swizzled [88][32]: XOR (c>>2)&7 into pos bits 2..4
        *(f32x4*)(lds + c * WT_ + (posoff ^ (((c >> 2) & 7) << 2))) = tv;
    }

    __syncthreads();   // 1 wave: just the lgkmcnt fence, barrier is free

    // write phase: 32*88 = 704 f4, contiguous NT stores
    const int ob = pbase * CH_;
    #pragma unroll
    for (int i = 0; i < 11; ++i) {
        int f   = i * 64 + lane;
        int pos = f / 22;
        int c4  = f - 22 * pos;                // channel group c=4*c4+k
        int bse = c4 * 128 + (pos ^ ((c4 & 7) << 2));
        f32x4 o;
        #pragma unroll
        for (int k = 0; k < 4; ++k) o[k] = lds[bse + 32 * k];
        __builtin_nontemporal_store(o, (f32x4*)(out + ob + f * 4));
    }

    for (int off = 32; off; off >>= 1) noobj += __shfl_xor(noobj, off);
    if (lane == 0) atomicAdd(&ws[bid & 63], (double)noobj);
}

// --- target path: one wave per target ---
__device__ __forceinline__ void tgt_wave(int n, const float* __restrict__ x,
                                         const float* __restrict__ tgt,
                                         const float* __restrict__ anchors,
                                         double* __restrict__ ws, int lane) {
    const float* t = tgt + n * CH_;

    float a_w[3], a_h[3];
    #pragma unroll
    for (int a = 0; a < 3; ++a) { a_w[a] = anchors[2*a]; a_h[a] = anchors[2*a+1]; }

    int   bi  = (int)t[0];
    float tcx = t[1] * (float)G_;
    float tcy = t[2] * (float)G_;
    float tw  = t[3], th = t[4], tistop = t[5];
    int   ci  = (int)tcx;
    int   cj  = (int)tcy;
    int   q   = cj * G_ + ci;

    float iou[3];
    int best = 0;
    float best_iou = -1.0f;
    #pragma unroll
    for (int a = 0; a < 3; ++a) {
        float inter = fminf(a_w[a], tw) * fminf(a_h[a], th);
        float uni   = tw * th + a_w[a] * a_h[a] - inter + 1e-16f;
        iou[a] = inter / uni;
        if (iou[a] > best_iou) { best_iou = iou[a]; best = a; }
    }

    const float* cell = x + (bi * 3 + best) * CH_ * GG_ + q;
    bool is_top = tistop > 0.5f;
    int  c0 = is_top ? 0 : NTOP_;
    int  nc = is_top ? NTOP_ : (CTOT_ - NTOP_);

    float cls_s = 0.0f, s512 = 0.0f, nsub = 0.0f;
    if (lane < nc) {
        int c = c0 + lane;
        float p  = sigf(cell[(6 + c) * GG_]);
        float tv = t[6 + c];
        cls_s = -(tv * fmaxf(logf(p), -100.0f) +
                  (1.0f - tv) * fmaxf(log1pf(-p), -100.0f));
    } else if (lane >= 56 && lane < 60) {
        int k = lane - 56;
        float v = cell[k * GG_];
        float tv;
        if      (k == 0) tv = tcx - floorf(tcx);
        else if (k == 1) tv = tcy - floorf(tcy);
        else if (k == 2) tv = logf(tw / a_w[best] + 1e-16f);
        else             tv = logf(th / a_h[best] + 1e-16f);
        float d = (k < 2 ? sigf(v) : v) - tv;
        s512 = d * d;
    } else if (lane == 60) {
        float pc = sigf(cell[4 * GG_]);
        float pt = sigf(cell[5 * GG_]);
        s512 = -fmaxf(logf(pc), -100.0f)
             - (tistop * fmaxf(logf(pt), -100.0f) +
                (1.0f - tistop) * fmaxf(log1pf(-pt), -100.0f));
    } else if (lane >= 61) {
        int a = lane - 61;
        if (iou[a] > 0.5f || a == best) {
            float p = sigf(x[((bi * 3 + a) * CH_ + 4) * GG_ + q]);
            nsub = -fmaxf(log1pf(-p), -100.0f);
        }
    }

    for (int off = 32; off; off >>= 1) {
        s512  += __shfl_xor(s512, off);
        cls_s += __shfl_xor(cls_s, off);
        nsub  += __shfl_xor(nsub, off);
    }
    if (lane == 0) {
        int slot = n & 7;
        float hitc = 0.0f;
        #pragma unroll
        for (int a = 0; a < 3; ++a)
            if (iou[a] > 0.5f || a == best) hitc += 1.0f;
        atomicAdd(&ws[64 + slot], (double)s512);
        if (is_top) {
            atomicAdd(&ws[72 + slot],  (double)cls_s);
            atomicAdd(&ws[104 + slot], (double)NTOP_);
        } else {
            atomicAdd(&ws[80 + slot],  (double)cls_s);
            atomicAdd(&ws[112 + slot], (double)(CTOT_ - NTOP_));
        }
        atomicAdd(&ws[88 + slot], (double)nsub);
        atomicAdd(&ws[96 + slot], (double)hitc);
    }
}

// --- finalize: last wave composes the loss (atomic reads bypass stale L1) ---
__device__ __forceinline__ void finalize_wave(double* __restrict__ ws,
                                              float* __restrict__ out, int lane) {
    double nb = atomicAdd(&ws[lane], 0.0);
    for (int off = 32; off; off >>= 1) nb += __shfl_xor(nb, off);

    double gv = (lane < 56) ? atomicAdd(&ws[64 + lane], 0.0) : 0.0;
    for (int off = 4; off; off >>= 1) gv += __shfl_xor(gv, off);

    double s512 = __shfl(gv, 0);
    double itm  = __shfl(gv, 8);
    double ibm  = __shfl(gv, 16);
    double nsub = __shfl(gv, 24);
    double hitc = __shfl(gv, 32);
    double itmc = __shfl(gv, 40);
    double ibmc = __shfl(gv, 48);

    if (lane == 0) {
        double nob  = nb - nsub;
        double nobc = (double)PTOT_ - hitc;
        double loss = s512 / 512.0
                    + 10.0 * ((nobc > 0.0) ? nob / fmax(nobc, 1.0) : 0.0)
                    + ((itmc > 0.0) ? itm / fmax(itmc, 1.0) : 0.0)
                    + ((ibmc > 0.0) ? ibm / fmax(ibmc, 1.0) : 0.0);
        out[PTOT_ * CH_] = (float)loss;
    }
}

__global__ __launch_bounds__(64, 4) void yolo_fused(const float* __restrict__ x,
                                                    const float* __restrict__ tgt,
                                                    const float* __restrict__ anchors,
                                                    float* __restrict__ out,
                                                    double* __restrict__ ws) {
    __shared__ float lds[CH_ * WT_];
    const int orig = blockIdx.x;
    const int lane = threadIdx.x;

    if (orig < NBM_) {
        // bijective XCD-chunked swizzle (8112 = 8*1014 exact)
        int bid = (orig & 7) * XCHUNK_ + (orig >> 3);
        main_wave(bid, x, anchors, out, ws, lds, lane);
    } else {
        tgt_wave(orig - NBM_, x, tgt, anchors, ws, lane);
    }

    // last-block-done finalize
    __threadfence();
    unsigned old = 0;
    if (lane == 0)
        old = atomicAdd((unsigned int*)(ws + 120), 1u);
    old = __shfl(old, 0);
    if (old == NBT_ - 1) {
        __threadfence();
        finalize_wave(ws, out, lane);
    }
}

extern "C" void kernel_launch(void* const* d_in, const int* in_sizes, int n_in,
                              void* d_out, int out_size, void* d_ws, size_t ws_size,
                              hipStream_t stream) {
    const float* x       = (const float*)d_in[0];
    const float* target  = (const float*)d_in[1];
    const float* anchors = (const float*)d_in[2];
    float*  out = (float*)d_out;
    double* ws  = (double*)d_ws;

    // zero accumulators + done-counter every call
    hipMemsetAsync(d_ws, 0, 121 * sizeof(double), stream);

    yolo_fused<<<dim3(NBT_), dim3(64), 0, stream>>>(x, target, anchors, out, ws);
}

// Round 5
// 54.534 us; speedup vs baseline: 5.8545x; 5.8545x over previous
//
#include <hip/hip_runtime.h>

// Problem constants
#define G_      52
#define GG_     2704          // G*G
#define CH_     88            // 5+1+C
#define NTOP_   53
#define CTOT_   82
#define PTOT_   259584        // B*A*G*G
#define NTGT_   512
#define QT_     128           // positions per tile
#define NB_     2028          // PTOT/QT
#define XQ_     253           // NB/8
#define XR_     4             // NB%8

typedef float f32x4 __attribute__((ext_vector_type(4)));

__device__ __forceinline__ float sigf(float v) {
    return 1.0f / (1.0f + __expf(-v));
}

// ws layout (doubles):
//  [0..63]    noobj_all partials
//  [64..71]   s512  [72..79] itm  [80..87] ibm
//  [88..95]   nsub  [96..103] hitc  [104..111] itmc  [112..119] ibmc

__global__ __launch_bounds__(256) void yolo_main(const float* __restrict__ x,
                                                 const float* __restrict__ anchors,
                                                 float* __restrict__ out,
                                                 double* __restrict__ ws) {
    __shared__ float lds[CH_ * QT_];
    const int tid = threadIdx.x;

    // bijective XCD-chunked swizzle (2028 = 8*253 + 4)
    const int orig = blockIdx.x;
    const int xcd  = orig & 7;
    const int lin  = orig >> 3;
    const int bid  = (xcd < XR_ ? xcd * (XQ_ + 1)
                                : XR_ * (XQ_ + 1) + (xcd - XR_) * XQ_) + lin;
    const int pbase = bid * QT_;

    const int c0   = tid >> 5;            // base channel 0..7 (half-wave each)
    const int poff = (tid & 31) * 4;      // f4 start within tile
    const int p    = pbase + poff;
    const int ba   = p / GG_;             // f4 never crosses ba (GG%4==0)
    const int q    = p - ba * GG_;
    const float* src = x + (ba * CH_ + c0) * GG_ + q;

    // ---- issue ALL 11 loads up front (deep pipeline, ~44 VGPR staged) ----
    f32x4 r[11];
    #pragma unroll
    for (int i = 0; i < 11; ++i)
        r[i] = *(const f32x4*)(src + i * 8 * GG_);

    float noobj = 0.0f;

    // ---- stage A: transform + LDS-write channels 0..39 (i = 0..4) ----
    #pragma unroll
    for (int i = 0; i < 5; ++i) {
        const int c = i * 8 + c0;
        f32x4 v = r[i];
        f32x4 tv;
        if (i == 0 && c0 < 4) {
            if (c0 == 0) {
                int gx = q % G_;          // q, G_ mult of 4 -> gx+3 <= 51
                #pragma unroll
                for (int k = 0; k < 4; ++k)
                    tv[k] = ((float)(gx + k) + sigf(v[k])) * 8.0f;
            } else if (c0 == 1) {
                int gy = q / G_;          // constant across the f4
                #pragma unroll
                for (int k = 0; k < 4; ++k)
                    tv[k] = ((float)gy + sigf(v[k])) * 8.0f;
            } else {                      // c0==2 (w) or c0==3 (h)
                int m = ba - (ba / 3) * 3;
                float anc = anchors[2 * m + (c0 - 2)];
                #pragma unroll
                for (int k = 0; k < 4; ++k)
                    tv[k] = anc * __expf(v[k]) * 416.0f;
            }
        } else {
            #pragma unroll
            for (int k = 0; k < 4; ++k) tv[k] = sigf(v[k]);
            if (i == 0 && c0 == 4) {      // conf channel: all-cells no-obj BCE
                #pragma unroll
                for (int k = 0; k < 4; ++k)
                    noobj -= fmaxf(log1pf(-tv[k]), -100.0f);
            }
        }
        *(f32x4*)(lds + c * QT_ + (poff ^ (((c >> 2) & 7) << 2))) = tv;
    }

    // noobj partial (c==4 lives in wave 2: tid in [128,160))
    if ((tid >> 6) == 2) {
        for (int off = 32; off; off >>= 1)
            noobj += __shfl_xor(noobj, off);
        if (tid == 128)
            atomicAdd(&ws[bid & 63], (double)noobj);
    }

    // lgkm-only barrier: do NOT drain vmcnt (stage-B loads stay in flight)
    asm volatile("s_waitcnt lgkmcnt(0)" ::: "memory");
    __builtin_amdgcn_s_barrier();
    asm volatile("" ::: "memory");

    // ---- out-write A: c4 0..9 (1280 f4) — overlaps stage-B load returns ----
    const int ob = pbase * CH_;
    #pragma unroll
    for (int it = 0; it < 5; ++it) {
        int j   = it * 256 + tid;
        int pos = j / 10;
        int c4  = j - 10 * pos;
        int bse = (4 * c4) * QT_ + (pos ^ ((c4 & 7) << 2));
        f32x4 o;
        #pragma unroll
        for (int k = 0; k < 4; ++k) o[k] = lds[bse + k * QT_];
        *(f32x4*)(out + ob + (pos * 22 + c4) * 4) = o;
    }

    // ---- stage B: transform + LDS-write channels 40..87 (i = 5..10) ----
    #pragma unroll
    for (int i = 5; i < 11; ++i) {
        const int c = i * 8 + c0;
        f32x4 v = r[i];
        f32x4 tv;
        #pragma unroll
        for (int k = 0; k < 4; ++k) tv[k] = sigf(v[k]);
        *(f32x4*)(lds + c * QT_ + (poff ^ (((c >> 2) & 7) << 2))) = tv;
    }

    asm volatile("s_waitcnt lgkmcnt(0)" ::: "memory");
    __builtin_amdgcn_s_barrier();
    asm volatile("" ::: "memory");

    // ---- out-write B: c4 10..21 (1536 f4) ----
    #pragma unroll
    for (int it = 0; it < 6; ++it) {
        int j   = it * 256 + tid;
        int pos = j / 12;
        int c4  = 10 + (j - 12 * pos);
        int bse = (4 * c4) * QT_ + (pos ^ ((c4 & 7) << 2));
        f32x4 o;
        #pragma unroll
        for (int k = 0; k < 4; ++k) o[k] = lds[bse + k * QT_];
        *(f32x4*)(out + ob + (pos * 22 + c4) * 4) = o;
    }
}

// One 64-lane wave per target: class-BCE channels one-per-lane,
// box/conf/istop/noobj-sub terms on lanes 56..63.
__global__ __launch_bounds__(64) void yolo_tgt(const float* __restrict__ x,
                                               const float* __restrict__ tgt,
                                               const float* __restrict__ anchors,
                                               double* __restrict__ ws) {
    const int n    = blockIdx.x;
    const int lane = threadIdx.x;
    const float* t = tgt + n * CH_;

    float a_w[3], a_h[3];
    #pragma unroll
    for (int a = 0; a < 3; ++a) { a_w[a] = anchors[2*a]; a_h[a] = anchors[2*a+1]; }

    int   bi  = (int)t[0];
    float tcx = t[1] * (float)G_;
    float tcy = t[2] * (float)G_;
    float tw  = t[3], th = t[4], tistop = t[5];
    int   ci  = (int)tcx;
    int   cj  = (int)tcy;
    int   q   = cj * G_ + ci;

    float iou[3];
    int best = 0;
    float best_iou = -1.0f;
    #pragma unroll
    for (int a = 0; a < 3; ++a) {
        float inter = fminf(a_w[a], tw) * fminf(a_h[a], th);
        float uni   = tw * th + a_w[a] * a_h[a] - inter + 1e-16f;
        iou[a] = inter / uni;
        if (iou[a] > best_iou) { best_iou = iou[a]; best = a; }
    }

    const float* cell = x + (bi * 3 + best) * CH_ * GG_ + q;
    bool is_top = tistop > 0.5f;
    int  c0 = is_top ? 0 : NTOP_;
    int  nc = is_top ? NTOP_ : (CTOT_ - NTOP_);

    float cls_s = 0.0f, s512 = 0.0f, nsub = 0.0f;
    if (lane < nc) {
        int c = c0 + lane;
        float pr = sigf(cell[(6 + c) * GG_]);
        float tv = t[6 + c];
        cls_s = -(tv * fmaxf(logf(pr), -100.0f) +
                  (1.0f - tv) * fmaxf(log1pf(-pr), -100.0f));
    } else if (lane >= 56 && lane < 60) {
        int k = lane - 56;
        float v = cell[k * GG_];
        float tv;
        if      (k == 0) tv = tcx - floorf(tcx);
        else if (k == 1) tv = tcy - floorf(tcy);
        else if (k == 2) tv = logf(tw / a_w[best] + 1e-16f);
        else             tv = logf(th / a_h[best] + 1e-16f);
        float d = (k < 2 ? sigf(v) : v) - tv;
        s512 = d * d;
    } else if (lane == 60) {
        float pc = sigf(cell[4 * GG_]);
        float pt = sigf(cell[5 * GG_]);
        s512 = -fmaxf(logf(pc), -100.0f)
             - (tistop * fmaxf(logf(pt), -100.0f) +
                (1.0f - tistop) * fmaxf(log1pf(-pt), -100.0f));
    } else if (lane >= 61) {
        int a = lane - 61;
        if (iou[a] > 0.5f || a == best) {
            float pr = sigf(x[((bi * 3 + a) * CH_ + 4) * GG_ + q]);
            nsub = -fmaxf(log1pf(-pr), -100.0f);
        }
    }

    for (int off = 32; off; off >>= 1) {
        s512  += __shfl_xor(s512, off);
        cls_s += __shfl_xor(cls_s, off);
        nsub  += __shfl_xor(nsub, off);
    }
    if (lane == 0) {
        int slot = n & 7;
        float hitc = 0.0f;
        #pragma unroll
        for (int a = 0; a < 3; ++a)
            if (iou[a] > 0.5f || a == best) hitc += 1.0f;
        atomicAdd(&ws[64 + slot], (double)s512);
        if (is_top) {
            atomicAdd(&ws[72 + slot],  (double)cls_s);
            atomicAdd(&ws[104 + slot], (double)NTOP_);
        } else {
            atomicAdd(&ws[80 + slot],  (double)cls_s);
            atomicAdd(&ws[112 + slot], (double)(CTOT_ - NTOP_));
        }
        atomicAdd(&ws[88 + slot], (double)nsub);
        atomicAdd(&ws[96 + slot], (double)hitc);
    }
}

__global__ __launch_bounds__(64) void yolo_final(const double* __restrict__ ws,
                                                 float* __restrict__ out) {
    const int lane = threadIdx.x;

    double nb = ws[lane];
    for (int off = 32; off; off >>= 1) nb += __shfl_xor(nb, off);

    double gv = (lane < 56) ? ws[64 + lane] : 0.0;
    for (int off = 4; off; off >>= 1) gv += __shfl_xor(gv, off);

    double s512 = __shfl(gv, 0);
    double itm  = __shfl(gv, 8);
    double ibm  = __shfl(gv, 16);
    double nsub = __shfl(gv, 24);
    double hitc = __shfl(gv, 32);
    double itmc = __shfl(gv, 40);
    double ibmc = __shfl(gv, 48);

    if (lane == 0) {
        double nob  = nb - nsub;
        double nobc = (double)PTOT_ - hitc;
        double loss = s512 / 512.0
                    + 10.0 * ((nobc > 0.0) ? nob / fmax(nobc, 1.0) : 0.0)
                    + ((itmc > 0.0) ? itm / fmax(itmc, 1.0) : 0.0)
                    + ((ibmc > 0.0) ? ibm / fmax(ibmc, 1.0) : 0.0);
        out[PTOT_ * CH_] = (float)loss;
    }
}

extern "C" void kernel_launch(void* const* d_in, const int* in_sizes, int n_in,
                              void* d_out, int out_size, void* d_ws, size_t ws_size,
                              hipStream_t stream) {
    const float* x       = (const float*)d_in[0];
    const float* target  = (const float*)d_in[1];
    const float* anchors = (const float*)d_in[2];
    float*  out = (float*)d_out;
    double* ws  = (double*)d_ws;

    hipMemsetAsync(d_ws, 0, 120 * sizeof(double), stream);

    yolo_main <<<dim3(NB_),   dim3(256), 0, stream>>>(x, anchors, out, ws);
    yolo_tgt  <<<dim3(NTGT_), dim3(64),  0, stream>>>(x, target, anchors, ws);
    yolo_final<<<dim3(1),     dim3(64),  0, stream>>>(ws, out);
}

// Round 6
// 47.687 us; speedup vs baseline: 6.6951x; 1.1436x over previous
//
#include <hip/hip_runtime.h>

// Problem constants
#define G_      52
#define GG_     2704          // G*G
#define CH_     88            // 5+1+C
#define NTOP_   53
#define CTOT_   82
#define PTOT_   259584        // B*A*G*G
#define NTGT_   512
#define QT_     128           // positions per tile
#define NT_     2028          // total tiles (PTOT/QT)
#define TPB_    4             // tiles per block
#define NB_     507           // blocks = NT/TPB (exact)
// XCD swizzle: 507 = 8*63 + 3 (chunks: 3 of 64, 5 of 63)

typedef float f32x4 __attribute__((ext_vector_type(4)));

__device__ __forceinline__ float sigf(float v) {
    return 1.0f / (1.0f + __expf(-v));
}

// lgkm-only barrier: does NOT drain vmcnt, so cross-tile global-load
// prefetch (and fire-and-forget stores) stay in flight across it.
__device__ __forceinline__ void lgkm_barrier() {
    asm volatile("s_waitcnt lgkmcnt(0)" ::: "memory");
    __builtin_amdgcn_s_barrier();
    asm volatile("" ::: "memory");
}

// ws layout (doubles):
//  [0..63]    noobj_all partials
//  [64..71]   s512  [72..79] itm  [80..87] ibm
//  [88..95]   nsub  [96..103] hitc  [104..111] itmc  [112..119] ibmc

// --- target path: one 64-lane wave per target ---
__device__ __forceinline__ void tgt_wave(int n, const float* __restrict__ x,
                                         const float* __restrict__ tgt,
                                         const float* __restrict__ anchors,
                                         double* __restrict__ ws, int lane) {
    const float* t = tgt + n * CH_;

    float a_w[3], a_h[3];
    #pragma unroll
    for (int a = 0; a < 3; ++a) { a_w[a] = anchors[2*a]; a_h[a] = anchors[2*a+1]; }

    int   bi  = (int)t[0];
    float tcx = t[1] * (float)G_;
    float tcy = t[2] * (float)G_;
    float tw  = t[3], th = t[4], tistop = t[5];
    int   ci  = (int)tcx;
    int   cj  = (int)tcy;
    int   q   = cj * G_ + ci;

    float iou[3];
    int best = 0;
    float best_iou = -1.0f;
    #pragma unroll
    for (int a = 0; a < 3; ++a) {
        float inter = fminf(a_w[a], tw) * fminf(a_h[a], th);
        float uni   = tw * th + a_w[a] * a_h[a] - inter + 1e-16f;
        iou[a] = inter / uni;
        if (iou[a] > best_iou) { best_iou = iou[a]; best = a; }
    }

    const float* cell = x + (bi * 3 + best) * CH_ * GG_ + q;
    bool is_top = tistop > 0.5f;
    int  c0 = is_top ? 0 : NTOP_;
    int  nc = is_top ? NTOP_ : (CTOT_ - NTOP_);

    float cls_s = 0.0f, s512 = 0.0f, nsub = 0.0f;
    if (lane < nc) {
        int c = c0 + lane;
        float pr = sigf(cell[(6 + c) * GG_]);
        float tv = t[6 + c];
        cls_s = -(tv * fmaxf(logf(pr), -100.0f) +
                  (1.0f - tv) * fmaxf(log1pf(-pr), -100.0f));
    } else if (lane >= 56 && lane < 60) {
        int k = lane - 56;
        float v = cell[k * GG_];
        float tv;
        if      (k == 0) tv = tcx - floorf(tcx);
        else if (k == 1) tv = tcy - floorf(tcy);
        else if (k == 2) tv = logf(tw / a_w[best] + 1e-16f);
        else             tv = logf(th / a_h[best] + 1e-16f);
        float d = (k < 2 ? sigf(v) : v) - tv;
        s512 = d * d;
    } else if (lane == 60) {
        float pc = sigf(cell[4 * GG_]);
        float pt = sigf(cell[5 * GG_]);
        s512 = -fmaxf(logf(pc), -100.0f)
             - (tistop * fmaxf(logf(pt), -100.0f) +
                (1.0f - tistop) * fmaxf(log1pf(-pt), -100.0f));
    } else if (lane >= 61) {
        int a = lane - 61;
        if (iou[a] > 0.5f || a == best) {
            float pr = sigf(x[((bi * 3 + a) * CH_ + 4) * GG_ + q]);
            nsub = -fmaxf(log1pf(-pr), -100.0f);
        }
    }

    for (int off = 32; off; off >>= 1) {
        s512  += __shfl_xor(s512, off);
        cls_s += __shfl_xor(cls_s, off);
        nsub  += __shfl_xor(nsub, off);
    }
    if (lane == 0) {
        int slot = n & 7;
        float hitc = 0.0f;
        #pragma unroll
        for (int a = 0; a < 3; ++a)
            if (iou[a] > 0.5f || a == best) hitc += 1.0f;
        atomicAdd(&ws[64 + slot], (double)s512);
        if (is_top) {
            atomicAdd(&ws[72 + slot],  (double)cls_s);
            atomicAdd(&ws[104 + slot], (double)NTOP_);
        } else {
            atomicAdd(&ws[80 + slot],  (double)cls_s);
            atomicAdd(&ws[112 + slot], (double)(CTOT_ - NTOP_));
        }
        atomicAdd(&ws[88 + slot], (double)nsub);
        atomicAdd(&ws[96 + slot], (double)hitc);
    }
}

// --- persistent main: 4 consecutive tiles/block, cross-tile reg prefetch ---
__global__ __launch_bounds__(256, 3) void yolo_pers(const float* __restrict__ x,
                                                    const float* __restrict__ tgt,
                                                    const float* __restrict__ anchors,
                                                    float* __restrict__ out,
                                                    double* __restrict__ ws) {
    __shared__ float lds[CH_ * QT_];
    const int tid  = threadIdx.x;
    const int orig = blockIdx.x;

    // bijective XCD-chunked swizzle (507 = 3*64 + 5*63)
    const int xcd = orig & 7;
    const int lin = orig >> 3;
    const int bid = (xcd < 3 ? xcd * 64 : 192 + (xcd - 3) * 63) + lin;

    const int c0   = tid >> 5;            // base channel 0..7 (half-wave each)
    const int poff = (tid & 31) * 4;      // f4 start within tile

    float noobj = 0.0f;
    f32x4 r[11];

    // prologue: issue tile-0 loads
    int tt = bid * TPB_;
    int p  = tt * QT_ + poff;
    int ba = p / GG_;                     // f4 never crosses ba (GG%4==0)
    int q  = p - ba * GG_;
    {
        const float* src = x + (ba * CH_ + c0) * GG_ + q;
        #pragma unroll
        for (int i = 0; i < 11; ++i)
            r[i] = *(const f32x4*)(src + i * 8 * GG_);
    }

    for (int j = 0; j < TPB_; ++j) {
        // next-tile geometry + src (computed even on last iter; not deref'd)
        int p2  = (tt + 1) * QT_ + poff;
        int ba2 = p2 / GG_;
        int q2  = p2 - ba2 * GG_;
        const float* src2 = x + (ba2 * CH_ + c0) * GG_ + q2;
        const bool more = (j + 1 < TPB_);   // uniform branch

        // transform tile t (regs ready since a full tile ago) and
        // interleave-issue tile t+1's loads into the freed registers
        #pragma unroll
        for (int i = 0; i < 11; ++i) {
            f32x4 v = r[i];
            if (more) r[i] = *(const f32x4*)(src2 + i * 8 * GG_);
            const int c = i * 8 + c0;
            f32x4 tv;
            if (i == 0 && c0 < 4) {
                if (c0 == 0) {
                    int gx = q % G_;      // q, G_ mult of 4 -> gx+3 <= 51
                    #pragma unroll
                    for (int k = 0; k < 4; ++k)
                        tv[k] = ((float)(gx + k) + sigf(v[k])) * 8.0f;
                } else if (c0 == 1) {
                    int gy = q / G_;      // constant across the f4
                    #pragma unroll
                    for (int k = 0; k < 4; ++k)
                        tv[k] = ((float)gy + sigf(v[k])) * 8.0f;
                } else {                  // c0==2 (w) or c0==3 (h)
                    int m = ba - (ba / 3) * 3;
                    float anc = anchors[2 * m + (c0 - 2)];
                    #pragma unroll
                    for (int k = 0; k < 4; ++k)
                        tv[k] = anc * __expf(v[k]) * 416.0f;
                }
            } else {
                #pragma unroll
                for (int k = 0; k < 4; ++k) tv[k] = sigf(v[k]);
                if (i == 0 && c0 == 4) {  // conf channel: all-cells no-obj BCE
                    #pragma unroll
                    for (int k = 0; k < 4; ++k)
                        noobj -= fmaxf(log1pf(-tv[k]), -100.0f);
                }
            }
            *(f32x4*)(lds + c * QT_ + (poff ^ (((c >> 2) & 7) << 2))) = tv;
        }

        lgkm_barrier();   // LDS writes visible; t+1 loads stay in flight

        // unified out-write: 2816 f4, contiguous 45 KB
        const int ob = tt * QT_ * CH_;
        #pragma unroll
        for (int it = 0; it < 11; ++it) {
            int j2  = it * 256 + tid;
            int pos = j2 / 22;
            int c4  = j2 - 22 * pos;
            int bse = 4 * c4 * QT_ + (pos ^ ((c4 & 7) << 2));
            f32x4 o;
            #pragma unroll
            for (int k = 0; k < 4; ++k) o[k] = lds[bse + k * QT_];
            *(f32x4*)(out + ob + j2 * 4) = o;
        }

        lgkm_barrier();   // all LDS reads done; safe to overwrite next iter

        tt += 1; ba = ba2; q = q2;
    }

    // noobj partials: c0==4 lanes are tid 128..159 (wave 2)
    if ((tid >> 6) == 2) {
        for (int off = 32; off; off >>= 1)
            noobj += __shfl_xor(noobj, off);
        if (tid == 128)
            atomicAdd(&ws[bid & 63], (double)noobj);
    }

    // fused target work on wave 0 (512 = 507 + 5)
    if (tid < 64) {
        tgt_wave(bid, x, tgt, anchors, ws, tid);
        if (bid < NTGT_ - NB_)
            tgt_wave(NB_ + bid, x, tgt, anchors, ws, tid);
    }
}

__global__ __launch_bounds__(64) void yolo_final(const double* __restrict__ ws,
                                                 float* __restrict__ out) {
    const int lane = threadIdx.x;

    double nb = ws[lane];
    for (int off = 32; off; off >>= 1) nb += __shfl_xor(nb, off);

    double gv = (lane < 56) ? ws[64 + lane] : 0.0;
    for (int off = 4; off; off >>= 1) gv += __shfl_xor(gv, off);

    double s512 = __shfl(gv, 0);
    double itm  = __shfl(gv, 8);
    double ibm  = __shfl(gv, 16);
    double nsub = __shfl(gv, 24);
    double hitc = __shfl(gv, 32);
    double itmc = __shfl(gv, 40);
    double ibmc = __shfl(gv, 48);

    if (lane == 0) {
        double nob  = nb - nsub;
        double nobc = (double)PTOT_ - hitc;
        double loss = s512 / 512.0
                    + 10.0 * ((nobc > 0.0) ? nob / fmax(nobc, 1.0) : 0.0)
                    + ((itmc > 0.0) ? itm / fmax(itmc, 1.0) : 0.0)
                    + ((ibmc > 0.0) ? ibm / fmax(ibmc, 1.0) : 0.0);
        out[PTOT_ * CH_] = (float)loss;
    }
}

extern "C" void kernel_launch(void* const* d_in, const int* in_sizes, int n_in,
                              void* d_out, int out_size, void* d_ws, size_t ws_size,
                              hipStream_t stream) {
    const float* x       = (const float*)d_in[0];
    const float* target  = (const float*)d_in[1];
    const float* anchors = (const float*)d_in[2];
    float*  out = (float*)d_out;
    double* ws  = (double*)d_ws;

    hipMemsetAsync(d_ws, 0, 120 * sizeof(double), stream);

    yolo_pers <<<dim3(NB_), dim3(256), 0, stream>>>(x, target, anchors, out, ws);
    yolo_final<<<dim3(1),   dim3(64),  0, stream>>>(ws, out);
}

// Round 7
// 45.948 us; speedup vs baseline: 6.9485x; 1.0378x over previous
//
#include <hip/hip_runtime.h>

// Problem constants
#define G_      52
#define GG_     2704          // G*G
#define CH_     88            // 5+1+C
#define NTOP_   53
#define CTOT_   82
#define PTOT_   259584        // B*A*G*G
#define NTGT_   512
#define QT_     128           // positions per tile
#define NT_     2028          // total tiles (PTOT/QT)
#define TPB_    2             // tiles per block
#define NB_     1014          // blocks = NT/TPB (exact)
// XCD swizzle: 1014 = 6*127 + 2*126

typedef float f32x4 __attribute__((ext_vector_type(4)));

__device__ __forceinline__ float sigf(float v) {
    return 1.0f / (1.0f + __expf(-v));
}

// lgkm-only barrier: does NOT drain vmcnt, so cross-tile global-load
// prefetch (and fire-and-forget stores) stay in flight across it.
__device__ __forceinline__ void lgkm_barrier() {
    asm volatile("s_waitcnt lgkmcnt(0)" ::: "memory");
    __builtin_amdgcn_s_barrier();
    asm volatile("" ::: "memory");
}

// ws layout (doubles):
//  [0..63]    noobj_all partials
//  [64..71]   s512  [72..79] itm  [80..87] ibm
//  [88..95]   nsub  [96..103] hitc  [104..111] itmc  [112..119] ibmc

// --- target path: one 64-lane wave per target ---
__device__ __forceinline__ void tgt_wave(int n, const float* __restrict__ x,
                                         const float* __restrict__ tgt,
                                         const float* __restrict__ anchors,
                                         double* __restrict__ ws, int lane) {
    const float* t = tgt + n * CH_;

    float a_w[3], a_h[3];
    #pragma unroll
    for (int a = 0; a < 3; ++a) { a_w[a] = anchors[2*a]; a_h[a] = anchors[2*a+1]; }

    int   bi  = (int)t[0];
    float tcx = t[1] * (float)G_;
    float tcy = t[2] * (float)G_;
    float tw  = t[3], th = t[4], tistop = t[5];
    int   ci  = (int)tcx;
    int   cj  = (int)tcy;
    int   q   = cj * G_ + ci;

    float iou[3];
    int best = 0;
    float best_iou = -1.0f;
    #pragma unroll
    for (int a = 0; a < 3; ++a) {
        float inter = fminf(a_w[a], tw) * fminf(a_h[a], th);
        float uni   = tw * th + a_w[a] * a_h[a] - inter + 1e-16f;
        iou[a] = inter / uni;
        if (iou[a] > best_iou) { best_iou = iou[a]; best = a; }
    }

    const float* cell = x + (bi * 3 + best) * CH_ * GG_ + q;
    bool is_top = tistop > 0.5f;
    int  c0 = is_top ? 0 : NTOP_;
    int  nc = is_top ? NTOP_ : (CTOT_ - NTOP_);

    float cls_s = 0.0f, s512 = 0.0f, nsub = 0.0f;
    if (lane < nc) {
        int c = c0 + lane;
        float pr = sigf(cell[(6 + c) * GG_]);
        float tv = t[6 + c];
        cls_s = -(tv * fmaxf(logf(pr), -100.0f) +
                  (1.0f - tv) * fmaxf(log1pf(-pr), -100.0f));
    } else if (lane >= 56 && lane < 60) {
        int k = lane - 56;
        float v = cell[k * GG_];
        float tv;
        if      (k == 0) tv = tcx - floorf(tcx);
        else if (k == 1) tv = tcy - floorf(tcy);
        else if (k == 2) tv = logf(tw / a_w[best] + 1e-16f);
        else             tv = logf(th / a_h[best] + 1e-16f);
        float d = (k < 2 ? sigf(v) : v) - tv;
        s512 = d * d;
    } else if (lane == 60) {
        float pc = sigf(cell[4 * GG_]);
        float pt = sigf(cell[5 * GG_]);
        s512 = -fmaxf(logf(pc), -100.0f)
             - (tistop * fmaxf(logf(pt), -100.0f) +
                (1.0f - tistop) * fmaxf(log1pf(-pt), -100.0f));
    } else if (lane >= 61) {
        int a = lane - 61;
        if (iou[a] > 0.5f || a == best) {
            float pr = sigf(x[((bi * 3 + a) * CH_ + 4) * GG_ + q]);
            nsub = -fmaxf(log1pf(-pr), -100.0f);
        }
    }

    for (int off = 32; off; off >>= 1) {
        s512  += __shfl_xor(s512, off);
        cls_s += __shfl_xor(cls_s, off);
        nsub  += __shfl_xor(nsub, off);
    }
    if (lane == 0) {
        int slot = n & 7;
        float hitc = 0.0f;
        #pragma unroll
        for (int a = 0; a < 3; ++a)
            if (iou[a] > 0.5f || a == best) hitc += 1.0f;
        atomicAdd(&ws[64 + slot], (double)s512);
        if (is_top) {
            atomicAdd(&ws[72 + slot],  (double)cls_s);
            atomicAdd(&ws[104 + slot], (double)NTOP_);
        } else {
            atomicAdd(&ws[80 + slot],  (double)cls_s);
            atomicAdd(&ws[112 + slot], (double)(CTOT_ - NTOP_));
        }
        atomicAdd(&ws[88 + slot], (double)nsub);
        atomicAdd(&ws[96 + slot], (double)hitc);
    }
}

// --- persistent main: 2 consecutive tiles/block, cross-tile reg prefetch ---
__global__ __launch_bounds__(256, 3) void yolo_pers(const float* __restrict__ x,
                                                    const float* __restrict__ tgt,
                                                    const float* __restrict__ anchors,
                                                    float* __restrict__ out,
                                                    double* __restrict__ ws) {
    __shared__ float lds[CH_ * QT_];
    const int tid  = threadIdx.x;
    const int orig = blockIdx.x;

    // bijective XCD-chunked swizzle (1014 = 6*127 + 2*126)
    const int xcd = orig & 7;
    const int lin = orig >> 3;
    const int bid = (xcd < 6 ? xcd * 127 : 762 + (xcd - 6) * 126) + lin;

    const int c0   = tid >> 5;            // base channel 0..7 (half-wave each)
    const int poff = (tid & 31) * 4;      // f4 start within tile

    float noobj = 0.0f;
    f32x4 r[11];

    // prologue: issue tile-0 loads
    int tt = bid * TPB_;
    int p  = tt * QT_ + poff;
    int ba = p / GG_;                     // f4 never crosses ba (GG%4==0)
    int q  = p - ba * GG_;
    {
        const float* src = x + (ba * CH_ + c0) * GG_ + q;
        #pragma unroll
        for (int i = 0; i < 11; ++i)
            r[i] = *(const f32x4*)(src + i * 8 * GG_);
    }

    #pragma unroll
    for (int j = 0; j < TPB_; ++j) {
        // next-tile geometry + src (computed even on last iter; not deref'd)
        int p2  = (tt + 1) * QT_ + poff;
        int ba2 = p2 / GG_;
        int q2  = p2 - ba2 * GG_;
        const float* src2 = x + (ba2 * CH_ + c0) * GG_ + q2;
        const bool more = (j + 1 < TPB_);   // uniform branch

        // transform tile t (regs ready since a full tile ago) and
        // interleave-issue tile t+1's loads into the freed registers
        #pragma unroll
        for (int i = 0; i < 11; ++i) {
            f32x4 v = r[i];
            if (more) r[i] = *(const f32x4*)(src2 + i * 8 * GG_);
            const int c = i * 8 + c0;
            f32x4 tv;
            if (i == 0 && c0 < 4) {
                if (c0 == 0) {
                    int gx = q % G_;      // q, G_ mult of 4 -> gx+3 <= 51
                    #pragma unroll
                    for (int k = 0; k < 4; ++k)
                        tv[k] = ((float)(gx + k) + sigf(v[k])) * 8.0f;
                } else if (c0 == 1) {
                    int gy = q / G_;      // constant across the f4
                    #pragma unroll
                    for (int k = 0; k < 4; ++k)
                        tv[k] = ((float)gy + sigf(v[k])) * 8.0f;
                } else {                  // c0==2 (w) or c0==3 (h)
                    int m = ba - (ba / 3) * 3;
                    float anc = anchors[2 * m + (c0 - 2)];
                    #pragma unroll
                    for (int k = 0; k < 4; ++k)
                        tv[k] = anc * __expf(v[k]) * 416.0f;
                }
            } else {
                #pragma unroll
                for (int k = 0; k < 4; ++k) tv[k] = sigf(v[k]);
                if (i == 0 && c0 == 4) {  // conf channel: all-cells no-obj BCE
                    #pragma unroll
                    for (int k = 0; k < 4; ++k)
                        noobj -= fmaxf(log1pf(-tv[k]), -100.0f);
                }
            }
            *(f32x4*)(lds + c * QT_ + (poff ^ (((c >> 2) & 7) << 2))) = tv;
        }

        lgkm_barrier();   // LDS writes visible; t+1 loads stay in flight

        // unified out-write: 2816 f4, contiguous 45 KB
        const int ob = tt * QT_ * CH_;
        #pragma unroll
        for (int it = 0; it < 11; ++it) {
            int j2  = it * 256 + tid;
            int pos = j2 / 22;
            int c4  = j2 - 22 * pos;
            int bse = 4 * c4 * QT_ + (pos ^ ((c4 & 7) << 2));
            f32x4 o;
            #pragma unroll
            for (int k = 0; k < 4; ++k) o[k] = lds[bse + k * QT_];
            *(f32x4*)(out + ob + j2 * 4) = o;
        }

        lgkm_barrier();   // all LDS reads done; safe to overwrite next iter

        tt += 1; ba = ba2; q = q2;
    }

    // noobj partials: c0==4 lanes are tid 128..159 (wave 2)
    if ((tid >> 6) == 2) {
        for (int off = 32; off; off >>= 1)
            noobj += __shfl_xor(noobj, off);
        if (tid == 128)
            atomicAdd(&ws[bid & 63], (double)noobj);
    }

    // fused target work on wave 0 (1014 blocks >= 512 targets)
    if (tid < 64 && bid < NTGT_) {
        tgt_wave(bid, x, tgt, anchors, ws, tid);
    }
}

__global__ __launch_bounds__(64) void yolo_final(const double* __restrict__ ws,
                                                 float* __restrict__ out) {
    const int lane = threadIdx.x;

    double nb = ws[lane];
    for (int off = 32; off; off >>= 1) nb += __shfl_xor(nb, off);

    double gv = (lane < 56) ? ws[64 + lane] : 0.0;
    for (int off = 4; off; off >>= 1) gv += __shfl_xor(gv, off);

    double s512 = __shfl(gv, 0);
    double itm  = __shfl(gv, 8);
    double ibm  = __shfl(gv, 16);
    double nsub = __shfl(gv, 24);
    double hitc = __shfl(gv, 32);
    double itmc = __shfl(gv, 40);
    double ibmc = __shfl(gv, 48);

    if (lane == 0) {
        double nob  = nb - nsub;
        double nobc = (double)PTOT_ - hitc;
        double loss = s512 / 512.0
                    + 10.0 * ((nobc > 0.0) ? nob / fmax(nobc, 1.0) : 0.0)
                    + ((itmc > 0.0) ? itm / fmax(itmc, 1.0) : 0.0)
                    + ((ibmc > 0.0) ? ibm / fmax(ibmc, 1.0) : 0.0);
        out[PTOT_ * CH_] = (float)loss;
    }
}

extern "C" void kernel_launch(void* const* d_in, const int* in_sizes, int n_in,
                              void* d_out, int out_size, void* d_ws, size_t ws_size,
                              hipStream_t stream) {
    const float* x       = (const float*)d_in[0];
    const float* target  = (const float*)d_in[1];
    const float* anchors = (const float*)d_in[2];
    float*  out = (float*)d_out;
    double* ws  = (double*)d_ws;

    hipMemsetAsync(d_ws, 0, 120 * sizeof(double), stream);

    yolo_pers <<<dim3(NB_), dim3(256), 0, stream>>>(x, target, anchors, out, ws);
    yolo_final<<<dim3(1),   dim3(64),  0, stream>>>(ws, out);
}

// Round 8
// 45.267 us; speedup vs baseline: 7.0530x; 1.0150x over previous
//
#include <hip/hip_runtime.h>

// Problem constants
#define G_      52
#define GG_     2704          // G*G
#define CH_     88            // 5+1+C
#define NTOP_   53
#define CTOT_   82
#define PTOT_   259584        // B*A*G*G
#define NTGT_   512
#define QT_     64            // positions per tile
#define TPB_    2             // tiles per block
#define NB_     2028          // blocks = PTOT/(QT*TPB)
#define TOFF_   2048          // ws offset of per-target tuples
// XCD swizzle: 2028 = 4*254 + 4*253

typedef float f32x4 __attribute__((ext_vector_type(4)));

__device__ __forceinline__ float sigf(float v) {
    return 1.0f / (1.0f + __expf(-v));
}

// lgkm-only barrier: does NOT drain vmcnt, so cross-tile global-load
// prefetch stays in flight across it.
__device__ __forceinline__ void lgkm_barrier() {
    asm volatile("s_waitcnt lgkmcnt(0)" ::: "memory");
    __builtin_amdgcn_s_barrier();
    asm volatile("" ::: "memory");
}

// ws layout (doubles) — ALL slots are plain-stored (no atomics, no zeroing):
//  [0..2027]        per-block noobj_all partials
//  [2048 + 8n + k]  per-target tuple: {s512, itm, ibm, nsub, hitc, itmc, ibmc}

// --- target path: one 64-lane wave per target, unique-slot writes ---
__device__ __forceinline__ void tgt_wave(int n, const float* __restrict__ x,
                                         const float* __restrict__ tgt,
                                         const float* __restrict__ anchors,
                                         double* __restrict__ ws, int lane) {
    const float* t = tgt + n * CH_;

    float a_w[3], a_h[3];
    #pragma unroll
    for (int a = 0; a < 3; ++a) { a_w[a] = anchors[2*a]; a_h[a] = anchors[2*a+1]; }

    int   bi  = (int)t[0];
    float tcx = t[1] * (float)G_;
    float tcy = t[2] * (float)G_;
    float tw  = t[3], th = t[4], tistop = t[5];
    int   ci  = (int)tcx;
    int   cj  = (int)tcy;
    int   q   = cj * G_ + ci;

    float iou[3];
    int best = 0;
    float best_iou = -1.0f;
    #pragma unroll
    for (int a = 0; a < 3; ++a) {
        float inter = fminf(a_w[a], tw) * fminf(a_h[a], th);
        float uni   = tw * th + a_w[a] * a_h[a] - inter + 1e-16f;
        iou[a] = inter / uni;
        if (iou[a] > best_iou) { best_iou = iou[a]; best = a; }
    }

    const float* cell = x + (bi * 3 + best) * CH_ * GG_ + q;
    bool is_top = tistop > 0.5f;
    int  c0 = is_top ? 0 : NTOP_;
    int  nc = is_top ? NTOP_ : (CTOT_ - NTOP_);

    float cls_s = 0.0f, s512 = 0.0f, nsub = 0.0f;
    if (lane < nc) {
        int c = c0 + lane;
        float pr = sigf(cell[(6 + c) * GG_]);
        float tv = t[6 + c];
        cls_s = -(tv * fmaxf(logf(pr), -100.0f) +
                  (1.0f - tv) * fmaxf(log1pf(-pr), -100.0f));
    } else if (lane >= 56 && lane < 60) {
        int k = lane - 56;
        float v = cell[k * GG_];
        float tv;
        if      (k == 0) tv = tcx - floorf(tcx);
        else if (k == 1) tv = tcy - floorf(tcy);
        else if (k == 2) tv = logf(tw / a_w[best] + 1e-16f);
        else             tv = logf(th / a_h[best] + 1e-16f);
        float d = (k < 2 ? sigf(v) : v) - tv;
        s512 = d * d;
    } else if (lane == 60) {
        float pc = sigf(cell[4 * GG_]);
        float pt = sigf(cell[5 * GG_]);
        s512 = -fmaxf(logf(pc), -100.0f)
             - (tistop * fmaxf(logf(pt), -100.0f) +
                (1.0f - tistop) * fmaxf(log1pf(-pt), -100.0f));
    } else if (lane >= 61) {
        int a = lane - 61;
        if (iou[a] > 0.5f || a == best) {
            float pr = sigf(x[((bi * 3 + a) * CH_ + 4) * GG_ + q]);
            nsub = -fmaxf(log1pf(-pr), -100.0f);
        }
    }

    for (int off = 32; off; off >>= 1) {
        s512  += __shfl_xor(s512, off);
        cls_s += __shfl_xor(cls_s, off);
        nsub  += __shfl_xor(nsub, off);
    }
    if (lane == 0) {
        float hitc = 0.0f;
        #pragma unroll
        for (int a = 0; a < 3; ++a)
            if (iou[a] > 0.5f || a == best) hitc += 1.0f;
        double* e = ws + TOFF_ + n * 8;
        e[0] = (double)s512;
        e[1] = is_top ? (double)cls_s : 0.0;
        e[2] = is_top ? 0.0 : (double)cls_s;
        e[3] = (double)nsub;
        e[4] = (double)hitc;
        e[5] = is_top ? (double)NTOP_ : 0.0;
        e[6] = is_top ? 0.0 : (double)(CTOT_ - NTOP_);
    }
}

// --- main: [88][64] tile, 2 tiles/block, cross-tile register prefetch ---
__global__ __launch_bounds__(256, 7) void yolo_pers(const float* __restrict__ x,
                                                    const float* __restrict__ tgt,
                                                    const float* __restrict__ anchors,
                                                    float* __restrict__ out,
                                                    double* __restrict__ ws) {
    __shared__ float lds[CH_ * QT_];     // 22528 B -> 7 blocks/CU
    const int tid  = threadIdx.x;
    const int orig = blockIdx.x;

    // bijective XCD-chunked swizzle (2028 = 4*254 + 4*253)
    const int xcd = orig & 7;
    const int lin = orig >> 3;
    const int bid = (xcd < 4 ? xcd * 254 : 1016 + (xcd - 4) * 253) + lin;

    const int cs   = tid >> 4;            // channel slot 0..15
    const int poff = (tid & 15) * 4;      // f4 start within tile

    float noobj = 0.0f;
    f32x4 r[6];

    int tt = bid * TPB_;

    // prologue: issue tile-0 loads (c = 16i + cs, masked at 88)
    {
        int p  = tt * QT_ + poff;
        int ba = p / GG_;                 // f4 never crosses ba (GG%4==0)
        int q  = p - ba * GG_;
        #pragma unroll
        for (int i = 0; i < 6; ++i) {
            int c = i * 16 + cs;
            if (c < CH_)
                r[i] = *(const f32x4*)(x + (ba * CH_ + c) * GG_ + q);
        }
    }

    #pragma unroll
    for (int j = 0; j < TPB_; ++j) {
        int p   = tt * QT_ + poff;
        int ba  = p / GG_;
        int q   = p - ba * GG_;
        int p2  = (tt + 1) * QT_ + poff;
        int ba2 = p2 / GG_;
        int q2  = p2 - ba2 * GG_;
        const bool more = (j + 1 < TPB_);   // uniform branch

        // transform tile t (regs ready since a full tile ago) and
        // interleave-issue tile t+1's loads into the freed registers
        #pragma unroll
        for (int i = 0; i < 6; ++i) {
            int c = i * 16 + cs;
            f32x4 v = r[i];
            if (more && c < CH_)
                r[i] = *(const f32x4*)(x + (ba2 * CH_ + c) * GG_ + q2);
            if (c < CH_) {
                f32x4 tv;
                if (i == 0 && cs < 5) {
                    if (cs == 0) {
                        int gx = q % G_;  // q, G_ mult of 4 -> gx+3 <= 51
                        #pragma unroll
                        for (int k = 0; k < 4; ++k)
                            tv[k] = ((float)(gx + k) + sigf(v[k])) * 8.0f;
                    } else if (cs == 1) {
                        int gy = q / G_;  // constant across the f4
                        #pragma unroll
                        for (int k = 0; k < 4; ++k)
                            tv[k] = ((float)gy + sigf(v[k])) * 8.0f;
                    } else if (cs < 4) {  // cs==2 (w) or cs==3 (h)
                        int m = ba - (ba / 3) * 3;
                        float anc = anchors[2 * m + (cs - 2)];
                        #pragma unroll
                        for (int k = 0; k < 4; ++k)
                            tv[k] = anc * __expf(v[k]) * 416.0f;
                    } else {              // cs==4: conf + all-cells no-obj BCE
                        #pragma unroll
                        for (int k = 0; k < 4; ++k) {
                            tv[k] = sigf(v[k]);
                            noobj -= fmaxf(log1pf(-tv[k]), -100.0f);
                        }
                    }
                } else {
                    #pragma unroll
                    for (int k = 0; k < 4; ++k) tv[k] = sigf(v[k]);
                }
                *(f32x4*)(lds + c * QT_ + (poff ^ (((c >> 2) & 7) << 2))) = tv;
            }
        }

        lgkm_barrier();   // LDS writes visible; t+1 loads stay in flight

        // out-write: 64*88 = 1408 f4, contiguous
        const int ob = tt * QT_ * CH_;
        #pragma unroll
        for (int it = 0; it < 6; ++it) {
            int j2 = it * 256 + tid;
            if (j2 < 1408) {
                int pos = j2 / 22;
                int c4  = j2 - 22 * pos;
                int bse = 4 * c4 * QT_ + (pos ^ ((c4 & 7) << 2));
                f32x4 o;
                #pragma unroll
                for (int k = 0; k < 4; ++k) o[k] = lds[bse + k * QT_];
                *(f32x4*)(out + ob + j2 * 4) = o;
            }
        }

        lgkm_barrier();   // all LDS reads done; safe to overwrite next iter
        tt += 1;
    }

    // noobj: nonzero only for tid 64..79 (wave 1); plain store, unique slot
    if ((tid >> 6) == 1) {
        for (int off = 32; off; off >>= 1)
            noobj += __shfl_xor(noobj, off);
        if (tid == 64)
            ws[bid] = (double)noobj;
    }

    // fused target work on wave 0 (2028 blocks >= 512 targets)
    if (tid < 64 && bid < NTGT_)
        tgt_wave(bid, x, tgt, anchors, ws, tid);
}

__global__ __launch_bounds__(256) void yolo_final(const double* __restrict__ ws,
                                                  float* __restrict__ out) {
    __shared__ double red[4][8];
    const int tid = threadIdx.x;

    double nb = 0.0, s512 = 0.0, itm = 0.0, ibm = 0.0;
    double nsub = 0.0, hitc = 0.0, itmc = 0.0, ibmc = 0.0;

    for (int i = tid; i < NB_; i += 256) nb += ws[i];
    for (int n = tid; n < NTGT_; n += 256) {
        const double* e = ws + TOFF_ + n * 8;
        s512 += e[0]; itm += e[1]; ibm += e[2]; nsub += e[3];
        hitc += e[4]; itmc += e[5]; ibmc += e[6];
    }

    for (int off = 32; off; off >>= 1) {
        nb   += __shfl_xor(nb, off);   s512 += __shfl_xor(s512, off);
        itm  += __shfl_xor(itm, off);  ibm  += __shfl_xor(ibm, off);
        nsub += __shfl_xor(nsub, off); hitc += __shfl_xor(hitc, off);
        itmc += __shfl_xor(itmc, off); ibmc += __shfl_xor(ibmc, off);
    }
    const int w = tid >> 6;
    if ((tid & 63) == 0) {
        red[w][0] = nb;   red[w][1] = s512; red[w][2] = itm;  red[w][3] = ibm;
        red[w][4] = nsub; red[w][5] = hitc; red[w][6] = itmc; red[w][7] = ibmc;
    }
    __syncthreads();

    if (tid == 0) {
        for (int w2 = 1; w2 < 4; ++w2) {
            red[0][0] += red[w2][0]; red[0][1] += red[w2][1];
            red[0][2] += red[w2][2]; red[0][3] += red[w2][3];
            red[0][4] += red[w2][4]; red[0][5] += red[w2][5];
            red[0][6] += red[w2][6]; red[0][7] += red[w2][7];
        }
        double nob  = red[0][0] - red[0][4];
        double nobc = (double)PTOT_ - red[0][5];
        double loss = red[0][1] / 512.0
                    + 10.0 * ((nobc > 0.0) ? nob / fmax(nobc, 1.0) : 0.0)
                    + ((red[0][6] > 0.0) ? red[0][2] / fmax(red[0][6], 1.0) : 0.0)
                    + ((red[0][7] > 0.0) ? red[0][3] / fmax(red[0][7], 1.0) : 0.0);
        out[PTOT_ * CH_] = (float)loss;
    }
}

extern "C" void kernel_launch(void* const* d_in, const int* in_sizes, int n_in,
                              void* d_out, int out_size, void* d_ws, size_t ws_size,
                              hipStream_t stream) {
    const float* x       = (const float*)d_in[0];
    const float* target  = (const float*)d_in[1];
    const float* anchors = (const float*)d_in[2];
    float*  out = (float*)d_out;
    double* ws  = (double*)d_ws;

    // no memset: every ws slot read by yolo_final is plain-stored each call
    yolo_pers <<<dim3(NB_), dim3(256), 0, stream>>>(x, target, anchors, out, ws);
    yolo_final<<<dim3(1),   dim3(256), 0, stream>>>(ws, out);
}

// Round 9
// 43.750 us; speedup vs baseline: 7.2976x; 1.0347x over previous
//
#include <hip/hip_runtime.h>

// Problem constants
#define G_      52
#define GG_     2704          // G*G
#define CH_     88            // 5+1+C
#define NTOP_   53
#define CTOT_   82
#define PTOT_   259584        // B*A*G*G
#define NTGT_   512
#define QT_     64            // positions per tile
#define TPB_    4             // tiles per block
#define NB_     1014          // blocks = PTOT/(QT*TPB)
#define TOFF_   2048          // ws offset of per-target tuples
// XCD swizzle: 1014 = 6*127 + 2*126

typedef float f32x4 __attribute__((ext_vector_type(4)));

__device__ __forceinline__ float sigf(float v) {
    return 1.0f / (1.0f + __expf(-v));
}

// lgkm-only barrier: does NOT drain vmcnt, so cross-tile global-load
// prefetch stays in flight across it.
__device__ __forceinline__ void lgkm_barrier() {
    asm volatile("s_waitcnt lgkmcnt(0)" ::: "memory");
    __builtin_amdgcn_s_barrier();
    asm volatile("" ::: "memory");
}

// ws layout (doubles) — ALL slots are plain-stored (no atomics, no zeroing):
//  [0..1013]        per-block noobj_all partials
//  [2048 + 8n + k]  per-target tuple: {s512, itm, ibm, nsub, hitc, itmc, ibmc}

// --- target path: one 64-lane wave per target, unique-slot writes ---
__device__ __forceinline__ void tgt_wave(int n, const float* __restrict__ x,
                                         const float* __restrict__ tgt,
                                         const float* __restrict__ anchors,
                                         double* __restrict__ ws, int lane) {
    const float* t = tgt + n * CH_;

    float a_w[3], a_h[3];
    #pragma unroll
    for (int a = 0; a < 3; ++a) { a_w[a] = anchors[2*a]; a_h[a] = anchors[2*a+1]; }

    int   bi  = (int)t[0];
    float tcx = t[1] * (float)G_;
    float tcy = t[2] * (float)G_;
    float tw  = t[3], th = t[4], tistop = t[5];
    int   ci  = (int)tcx;
    int   cj  = (int)tcy;
    int   q   = cj * G_ + ci;

    float iou[3];
    int best = 0;
    float best_iou = -1.0f;
    #pragma unroll
    for (int a = 0; a < 3; ++a) {
        float inter = fminf(a_w[a], tw) * fminf(a_h[a], th);
        float uni   = tw * th + a_w[a] * a_h[a] - inter + 1e-16f;
        iou[a] = inter / uni;
        if (iou[a] > best_iou) { best_iou = iou[a]; best = a; }
    }

    const float* cell = x + (bi * 3 + best) * CH_ * GG_ + q;
    bool is_top = tistop > 0.5f;
    int  c0 = is_top ? 0 : NTOP_;
    int  nc = is_top ? NTOP_ : (CTOT_ - NTOP_);

    float cls_s = 0.0f, s512 = 0.0f, nsub = 0.0f;
    if (lane < nc) {
        int c = c0 + lane;
        float pr = sigf(cell[(6 + c) * GG_]);
        float tv = t[6 + c];
        cls_s = -(tv * fmaxf(logf(pr), -100.0f) +
                  (1.0f - tv) * fmaxf(log1pf(-pr), -100.0f));
    } else if (lane >= 56 && lane < 60) {
        int k = lane - 56;
        float v = cell[k * GG_];
        float tv;
        if      (k == 0) tv = tcx - floorf(tcx);
        else if (k == 1) tv = tcy - floorf(tcy);
        else if (k == 2) tv = logf(tw / a_w[best] + 1e-16f);
        else             tv = logf(th / a_h[best] + 1e-16f);
        float d = (k < 2 ? sigf(v) : v) - tv;
        s512 = d * d;
    } else if (lane == 60) {
        float pc = sigf(cell[4 * GG_]);
        float pt = sigf(cell[5 * GG_]);
        s512 = -fmaxf(logf(pc), -100.0f)
             - (tistop * fmaxf(logf(pt), -100.0f) +
                (1.0f - tistop) * fmaxf(log1pf(-pt), -100.0f));
    } else if (lane >= 61) {
        int a = lane - 61;
        if (iou[a] > 0.5f || a == best) {
            float pr = sigf(x[((bi * 3 + a) * CH_ + 4) * GG_ + q]);
            nsub = -fmaxf(log1pf(-pr), -100.0f);
        }
    }

    for (int off = 32; off; off >>= 1) {
        s512  += __shfl_xor(s512, off);
        cls_s += __shfl_xor(cls_s, off);
        nsub  += __shfl_xor(nsub, off);
    }
    if (lane == 0) {
        float hitc = 0.0f;
        #pragma unroll
        for (int a = 0; a < 3; ++a)
            if (iou[a] > 0.5f || a == best) hitc += 1.0f;
        double* e = ws + TOFF_ + n * 8;
        e[0] = (double)s512;
        e[1] = is_top ? (double)cls_s : 0.0;
        e[2] = is_top ? 0.0 : (double)cls_s;
        e[3] = (double)nsub;
        e[4] = (double)hitc;
        e[5] = is_top ? (double)NTOP_ : 0.0;
        e[6] = is_top ? 0.0 : (double)(CTOT_ - NTOP_);
    }
}

// --- main: [88][64] tile, 4 tiles/block, cross-tile register prefetch ---
__global__ __launch_bounds__(256, 7) void yolo_pers(const float* __restrict__ x,
                                                    const float* __restrict__ tgt,
                                                    const float* __restrict__ anchors,
                                                    float* __restrict__ out,
                                                    double* __restrict__ ws) {
    __shared__ float lds[CH_ * QT_];     // 22528 B
    const int tid  = threadIdx.x;
    const int orig = blockIdx.x;

    // bijective XCD-chunked swizzle (1014 = 6*127 + 2*126)
    const int xcd = orig & 7;
    const int lin = orig >> 3;
    const int bid = (xcd < 6 ? xcd * 127 : 762 + (xcd - 6) * 126) + lin;

    const int cs   = tid >> 4;            // channel slot 0..15
    const int poff = (tid & 15) * 4;      // f4 start within tile

    float noobj = 0.0f;
    f32x4 r[6];

    int tt = bid * TPB_;

    // prologue: issue tile-0 loads (c = 16i + cs, masked at 88)
    {
        int p  = tt * QT_ + poff;
        int ba = p / GG_;                 // f4 never crosses ba (GG%4==0)
        int q  = p - ba * GG_;
        #pragma unroll
        for (int i = 0; i < 6; ++i) {
            int c = i * 16 + cs;
            if (c < CH_)
                r[i] = *(const f32x4*)(x + (ba * CH_ + c) * GG_ + q);
        }
    }

    #pragma unroll
    for (int j = 0; j < TPB_; ++j) {
        int p   = tt * QT_ + poff;
        int ba  = p / GG_;
        int q   = p - ba * GG_;
        int p2  = (tt + 1) * QT_ + poff;
        int ba2 = p2 / GG_;
        int q2  = p2 - ba2 * GG_;
        const bool more = (j + 1 < TPB_);   // compile-time per unrolled j

        // transform tile t (regs ready since a full tile ago) and
        // interleave-issue tile t+1's loads into the freed registers
        #pragma unroll
        for (int i = 0; i < 6; ++i) {
            int c = i * 16 + cs;
            f32x4 v = r[i];
            if (more && c < CH_)
                r[i] = *(const f32x4*)(x + (ba2 * CH_ + c) * GG_ + q2);
            if (c < CH_) {
                f32x4 tv;
                if (i == 0 && cs < 5) {
                    if (cs == 0) {
                        int gx = q % G_;  // q, G_ mult of 4 -> gx+3 <= 51
                        #pragma unroll
                        for (int k = 0; k < 4; ++k)
                            tv[k] = ((float)(gx + k) + sigf(v[k])) * 8.0f;
                    } else if (cs == 1) {
                        int gy = q / G_;  // constant across the f4
                        #pragma unroll
                        for (int k = 0; k < 4; ++k)
                            tv[k] = ((float)gy + sigf(v[k])) * 8.0f;
                    } else if (cs < 4) {  // cs==2 (w) or cs==3 (h)
                        int m = ba - (ba / 3) * 3;
                        float anc = anchors[2 * m + (cs - 2)];
                        #pragma unroll
                        for (int k = 0; k < 4; ++k)
                            tv[k] = anc * __expf(v[k]) * 416.0f;
                    } else {              // cs==4: conf + all-cells no-obj BCE
                        #pragma unroll
                        for (int k = 0; k < 4; ++k) {
                            tv[k] = sigf(v[k]);
                            noobj -= fmaxf(log1pf(-tv[k]), -100.0f);
                        }
                    }
                } else {
                    #pragma unroll
                    for (int k = 0; k < 4; ++k) tv[k] = sigf(v[k]);
                }
                *(f32x4*)(lds + c * QT_ + (poff ^ (((c >> 2) & 7) << 2))) = tv;
            }
        }

        lgkm_barrier();   // LDS writes visible; t+1 loads stay in flight

        // out-write: 64*88 = 1408 f4, contiguous; NON-TEMPORAL so the
        // output stream does not evict x from L3 between graph replays.
        const int ob = tt * QT_ * CH_;
        #pragma unroll
        for (int it = 0; it < 6; ++it) {
            int j2 = it * 256 + tid;
            if (j2 < 1408) {
                int pos = j2 / 22;
                int c4  = j2 - 22 * pos;
                int bse = 4 * c4 * QT_ + (pos ^ ((c4 & 7) << 2));
                f32x4 o;
                #pragma unroll
                for (int k = 0; k < 4; ++k) o[k] = lds[bse + k * QT_];
                __builtin_nontemporal_store(o, (f32x4*)(out + ob + j2 * 4));
            }
        }

        lgkm_barrier();   // all LDS reads done; safe to overwrite next iter
        tt += 1;
    }

    // noobj: nonzero only for tid 64..79 (wave 1); plain store, unique slot
    if ((tid >> 6) == 1) {
        for (int off = 32; off; off >>= 1)
            noobj += __shfl_xor(noobj, off);
        if (tid == 64)
            ws[bid] = (double)noobj;
    }

    // fused target work on wave 0 (1014 blocks >= 512 targets)
    if (tid < 64 && bid < NTGT_)
        tgt_wave(bid, x, tgt, anchors, ws, tid);
}

__global__ __launch_bounds__(256) void yolo_final(const double* __restrict__ ws,
                                                  float* __restrict__ out) {
    __shared__ double red[4][8];
    const int tid = threadIdx.x;

    double nb = 0.0, s512 = 0.0, itm = 0.0, ibm = 0.0;
    double nsub = 0.0, hitc = 0.0, itmc = 0.0, ibmc = 0.0;

    for (int i = tid; i < NB_; i += 256) nb += ws[i];
    for (int n = tid; n < NTGT_; n += 256) {
        const double* e = ws + TOFF_ + n * 8;
        s512 += e[0]; itm += e[1]; ibm += e[2]; nsub += e[3];
        hitc += e[4]; itmc += e[5]; ibmc += e[6];
    }

    for (int off = 32; off; off >>= 1) {
        nb   += __shfl_xor(nb, off);   s512 += __shfl_xor(s512, off);
        itm  += __shfl_xor(itm, off);  ibm  += __shfl_xor(ibm, off);
        nsub += __shfl_xor(nsub, off); hitc += __shfl_xor(hitc, off);
        itmc += __shfl_xor(itmc, off); ibmc += __shfl_xor(ibmc, off);
    }
    const int w = tid >> 6;
    if ((tid & 63) == 0) {
        red[w][0] = nb;   red[w][1] = s512; red[w][2] = itm;  red[w][3] = ibm;
        red[w][4] = nsub; red[w][5] = hitc; red[w][6] = itmc; red[w][7] = ibmc;
    }
    __syncthreads();

    if (tid == 0) {
        for (int w2 = 1; w2 < 4; ++w2) {
            red[0][0] += red[w2][0]; red[0][1] += red[w2][1];
            red[0][2] += red[w2][2]; red[0][3] += red[w2][3];
            red[0][4] += red[w2][4]; red[0][5] += red[w2][5];
            red[0][6] += red[w2][6]; red[0][7] += red[w2][7];
        }
        double nob  = red[0][0] - red[0][4];
        double nobc = (double)PTOT_ - red[0][5];
        double loss = red[0][1] / 512.0
                    + 10.0 * ((nobc > 0.0) ? nob / fmax(nobc, 1.0) : 0.0)
                    + ((red[0][6] > 0.0) ? red[0][2] / fmax(red[0][6], 1.0) : 0.0)
                    + ((red[0][7] > 0.0) ? red[0][3] / fmax(red[0][7], 1.0) : 0.0);
        out[PTOT_ * CH_] = (float)loss;
    }
}

extern "C" void kernel_launch(void* const* d_in, const int* in_sizes, int n_in,
                              void* d_out, int out_size, void* d_ws, size_t ws_size,
                              hipStream_t stream) {
    const float* x       = (const float*)d_in[0];
    const float* target  = (const float*)d_in[1];
    const float* anchors = (const float*)d_in[2];
    float*  out = (float*)d_out;
    double* ws  = (double*)d_ws;

    // no memset: every ws slot read by yolo_final is plain-stored each call
    yolo_pers <<<dim3(NB_), dim3(256), 0, stream>>>(x, target, anchors, out, ws);
    yolo_final<<<dim3(1),   dim3(256), 0, stream>>>(ws, out);
}